// Round 2
// baseline (27074.136 us; speedup 1.0000x reference)
//
#include <hip/hip_runtime.h>
#include <hip/hip_fp16.h>
#include <hip/hip_cooperative_groups.h>
#include <math.h>

namespace cg = cooperative_groups;

#define BB 512
#define HH 256
#define SS 168
#define TT 24
#define FIN 16
#define KC 32
#define TB 32
#define TU 32
#define XROW 288   // padded x0 row / padded dec_w_ih0 row (257 -> 288, zero-filled)
#define NBLK 256
#define NTHR 256

typedef unsigned long long ull;

__device__ __forceinline__ float sigf(float x) { return 1.f / (1.f + expf(-x)); }

struct SM {
  union {
    struct { float Xs[KC][TB + 1]; float Ws[KC][4 * TU + 4]; } l;  // 21120 B
    struct { float As[KC][65]; float Bs[KC][65]; } g;              // 16640 B
    struct { float qs[256], vs[256], sc[192], ctxs[512], sred[2]; } a;
  };
};

// ---------------------------------------------------------------------------
// Fused LSTM step tile: gates = bias + X@Wih^T + Hprev@Whh^T, then pointwise.
// Block tile 32b x 32u (128 gate cols); 256 thr: bq=tid&7 (4 b), ul=tid>>3.
// ---------------------------------------------------------------------------
__device__ void lstm_tile(
    int b0, int u0,
    const float* __restrict__ X, int rsX, int KIN,
    const float* __restrict__ Wih, int rsWih,
    const float* __restrict__ Hprev,
    const float* __restrict__ Whh,
    const float* __restrict__ bias,
    float* __restrict__ C, float* __restrict__ Hout,
    __half* __restrict__ E16out, ull eStrideB,
    float (*Xs)[TB + 1], float (*Ws)[4 * TU + 4])
{
  const int tid = threadIdx.x;
  const int bq = tid & 7;
  const int ul = tid >> 3;
  const int u = u0 + ul;

  float acc[4][4];
#pragma unroll
  for (int g = 0; g < 4; g++) {
    const float bv = bias[g * HH + u];
    acc[0][g] = bv; acc[1][g] = bv; acc[2][g] = bv; acc[3][g] = bv;
  }

#pragma unroll
  for (int ph = 0; ph < 2; ph++) {
    const float* A = ph ? Hprev : X;
    const float* W = ph ? Whh : Wih;
    const int rsA = ph ? HH : rsX;
    const int rsW = ph ? HH : rsWih;
    const int K = ph ? HH : KIN;
    for (int k0 = 0; k0 < K; k0 += KC) {
      const int kc = (KC < K - k0) ? KC : (K - k0);
      if (kc == KC && (rsA & 3) == 0) {
        const int bi = tid & 31, kq = tid >> 5;
        const float4 v = *(const float4*)(A + (ull)(b0 + bi) * rsA + k0 + kq * 4);
        Xs[kq * 4 + 0][bi] = v.x; Xs[kq * 4 + 1][bi] = v.y;
        Xs[kq * 4 + 2][bi] = v.z; Xs[kq * 4 + 3][bi] = v.w;
      } else {
        for (int idx = tid; idx < kc * 32; idx += 256) {
          const int bi = idx & 31, kk = idx >> 5;
          Xs[kk][bi] = A[(ull)(b0 + bi) * rsA + k0 + kk];
        }
      }
      if (kc == KC && (rsW & 3) == 0) {
        const int cl = tid & 127, kq = tid >> 7;
        const int j = (cl & 3) * HH + u0 + (cl >> 2);
        const float* gw = W + (ull)j * rsW + k0 + kq * 16;
#pragma unroll
        for (int i = 0; i < 4; i++) {
          const float4 v = *(const float4*)(gw + i * 4);
          const int kk = kq * 16 + i * 4;
          Ws[kk + 0][cl] = v.x; Ws[kk + 1][cl] = v.y;
          Ws[kk + 2][cl] = v.z; Ws[kk + 3][cl] = v.w;
        }
      } else {
        for (int idx = tid; idx < kc * 128; idx += 256) {
          const int cl = idx & 127, kk = idx >> 7;
          const int j = (cl & 3) * HH + u0 + (cl >> 2);
          Ws[kk][cl] = W[(ull)j * rsW + k0 + kk];
        }
      }
      __syncthreads();
      if (kc == KC) {
#pragma unroll 8
        for (int kk = 0; kk < KC; kk++) {
          const float4 xv = *(const float4*)&Xs[kk][bq * 4];
          const float4 wv = *(const float4*)&Ws[kk][ul * 4];
          acc[0][0] += xv.x * wv.x; acc[0][1] += xv.x * wv.y; acc[0][2] += xv.x * wv.z; acc[0][3] += xv.x * wv.w;
          acc[1][0] += xv.y * wv.x; acc[1][1] += xv.y * wv.y; acc[1][2] += xv.y * wv.z; acc[1][3] += xv.y * wv.w;
          acc[2][0] += xv.z * wv.x; acc[2][1] += xv.z * wv.y; acc[2][2] += xv.z * wv.z; acc[2][3] += xv.z * wv.w;
          acc[3][0] += xv.w * wv.x; acc[3][1] += xv.w * wv.y; acc[3][2] += xv.w * wv.z; acc[3][3] += xv.w * wv.w;
        }
      } else {
        for (int kk = 0; kk < kc; kk++) {
          const float4 xv = *(const float4*)&Xs[kk][bq * 4];
          const float4 wv = *(const float4*)&Ws[kk][ul * 4];
          acc[0][0] += xv.x * wv.x; acc[0][1] += xv.x * wv.y; acc[0][2] += xv.x * wv.z; acc[0][3] += xv.x * wv.w;
          acc[1][0] += xv.y * wv.x; acc[1][1] += xv.y * wv.y; acc[1][2] += xv.y * wv.z; acc[1][3] += xv.y * wv.w;
          acc[2][0] += xv.z * wv.x; acc[2][1] += xv.z * wv.y; acc[2][2] += xv.z * wv.z; acc[2][3] += xv.z * wv.w;
          acc[3][0] += xv.w * wv.x; acc[3][1] += xv.w * wv.y; acc[3][2] += xv.w * wv.z; acc[3][3] += xv.w * wv.w;
        }
      }
      __syncthreads();
    }
  }
#pragma unroll
  for (int bd = 0; bd < 4; bd++) {
    const int b = b0 + bq * 4 + bd;
    const float iv = sigf(acc[bd][0]);
    const float fv = sigf(acc[bd][1]);
    const float gv = tanhf(acc[bd][2]);
    const float ov = sigf(acc[bd][3]);
    const ull ci = (ull)b * HH + u;
    const float cn = fv * C[ci] + iv * gv;
    C[ci] = cn;
    const float hn = ov * tanhf(cn);
    Hout[ci] = hn;
    if (E16out) E16out[(ull)b * eStrideB + u] = __float2half(hn);
  }
}

// ---------------------------------------------------------------------------
// Generic 64x64 gemm tile: C[m][n] = bias[n] + sum_k A[m][k]*Bw[n][k]
// ---------------------------------------------------------------------------
template <typename AT, typename CT>
__device__ void gemm_tile(
    const AT* __restrict__ A, int rsA,
    const float* __restrict__ Bw, int rsB,
    const float* __restrict__ bias,
    CT* __restrict__ Cout, int rsC, int K, int m0, int n0,
    float (*As)[65], float (*Bs)[65])
{
  const int tid = threadIdx.x;
  const int mq = tid & 15, nq = tid >> 4;
  const int li = tid & 63, kq = tid >> 6;
  float acc[4][4] = {{0.f}};
  for (int k0 = 0; k0 < K; k0 += KC) {
    if constexpr (sizeof(AT) == 2) {
      float4 raw = *(const float4*)(A + (ull)(m0 + li) * rsA + k0 + kq * 8);
      const __half* hp = (const __half*)&raw;
#pragma unroll
      for (int i = 0; i < 8; i++) As[kq * 8 + i][li] = __half2float(hp[i]);
    } else {
      const float* ga = (const float*)A + (ull)(m0 + li) * rsA + k0 + kq * 8;
      const float4 v0 = *(const float4*)ga, v1 = *(const float4*)(ga + 4);
      As[kq * 8 + 0][li] = v0.x; As[kq * 8 + 1][li] = v0.y; As[kq * 8 + 2][li] = v0.z; As[kq * 8 + 3][li] = v0.w;
      As[kq * 8 + 4][li] = v1.x; As[kq * 8 + 5][li] = v1.y; As[kq * 8 + 6][li] = v1.z; As[kq * 8 + 7][li] = v1.w;
    }
    {
      const float* gb = Bw + (ull)(n0 + li) * rsB + k0 + kq * 8;
      const float4 v0 = *(const float4*)gb, v1 = *(const float4*)(gb + 4);
      Bs[kq * 8 + 0][li] = v0.x; Bs[kq * 8 + 1][li] = v0.y; Bs[kq * 8 + 2][li] = v0.z; Bs[kq * 8 + 3][li] = v0.w;
      Bs[kq * 8 + 4][li] = v1.x; Bs[kq * 8 + 5][li] = v1.y; Bs[kq * 8 + 6][li] = v1.z; Bs[kq * 8 + 7][li] = v1.w;
    }
    __syncthreads();
#pragma unroll 8
    for (int kk = 0; kk < KC; kk++) {
      const float4 a4 = *(const float4*)&As[kk][mq * 4];
      const float4 b4 = *(const float4*)&Bs[kk][nq * 4];
      acc[0][0] += a4.x * b4.x; acc[0][1] += a4.x * b4.y; acc[0][2] += a4.x * b4.z; acc[0][3] += a4.x * b4.w;
      acc[1][0] += a4.y * b4.x; acc[1][1] += a4.y * b4.y; acc[1][2] += a4.y * b4.z; acc[1][3] += a4.y * b4.w;
      acc[2][0] += a4.z * b4.x; acc[2][1] += a4.z * b4.y; acc[2][2] += a4.z * b4.z; acc[2][3] += a4.z * b4.w;
      acc[3][0] += a4.w * b4.x; acc[3][1] += a4.w * b4.y; acc[3][2] += a4.w * b4.z; acc[3][3] += a4.w * b4.w;
    }
    __syncthreads();
  }
#pragma unroll
  for (int i = 0; i < 4; i++) {
    const int m = m0 + mq * 4 + i;
    float r[4];
#pragma unroll
    for (int j = 0; j < 4; j++) r[j] = acc[i][j] + (bias ? bias[n0 + nq * 4 + j] : 0.f);
    if constexpr (sizeof(CT) == 2) {
      __half2* p = (__half2*)((__half*)Cout + (ull)m * rsC + n0 + nq * 4);
      __half2 h0; h0.x = __float2half(r[0]); h0.y = __float2half(r[1]);
      __half2 h1; h1.x = __float2half(r[2]); h1.y = __float2half(r[3]);
      p[0] = h0; p[1] = h1;
    } else {
      float4 v; v.x = r[0]; v.y = r[1]; v.z = r[2]; v.w = r[3];
      *(float4*)((float*)Cout + (ull)m * rsC + n0 + nq * 4) = v;
    }
  }
}

// ---------------------------------------------------------------------------
// Attention for one batch row b (block-wide). pos_bias omitted (softmax-inv).
// ---------------------------------------------------------------------------
__device__ void attn_one(int b, const float* __restrict__ q,
                         const __half* __restrict__ P16,
                         const __half* __restrict__ E16,
                         const float* __restrict__ attn_v,
                         float* __restrict__ x0, SM& sm)
{
  const int tid = threadIdx.x;
  __syncthreads();   // protect union reuse across sequential calls
  sm.a.qs[tid] = q[b * HH + tid];
  sm.a.vs[tid] = attn_v[tid];
  __syncthreads();
  const int wv = tid >> 6, lane = tid & 63;
  for (int s = wv; s < SS; s += 4) {
    const __half2* Pr = (const __half2*)(P16 + ((ull)b * SS + s) * HH);
    float a = 0.f;
#pragma unroll
    for (int jj = 0; jj < 2; jj++) {
      const int i2 = lane + 64 * jj;
      const float2 pv = __half22float2(Pr[i2]);
      const int g0 = i2 * 2;
      a += sm.a.vs[g0] * tanhf(pv.x + sm.a.qs[g0]);
      a += sm.a.vs[g0 + 1] * tanhf(pv.y + sm.a.qs[g0 + 1]);
    }
#pragma unroll
    for (int m = 32; m >= 1; m >>= 1) a += __shfl_xor(a, m, 64);
    if (lane == 0) sm.a.sc[s] = a;
  }
  __syncthreads();
  if (tid < 64) {
    float m = -1e30f;
    for (int i = tid; i < SS; i += 64) m = fmaxf(m, sm.a.sc[i]);
#pragma unroll
    for (int mm = 32; mm >= 1; mm >>= 1) m = fmaxf(m, __shfl_xor(m, mm, 64));
    if (tid == 0) sm.a.sred[0] = m;
  }
  __syncthreads();
  const float smax = sm.a.sred[0];
  if (tid < SS) sm.a.sc[tid] = expf(sm.a.sc[tid] - smax);
  __syncthreads();
  if (tid < 64) {
    float ssum = 0.f;
    for (int i = tid; i < SS; i += 64) ssum += sm.a.sc[i];
#pragma unroll
    for (int mm = 32; mm >= 1; mm >>= 1) ssum += __shfl_xor(ssum, mm, 64);
    if (tid == 0) sm.a.sred[1] = ssum;
  }
  __syncthreads();
  const float rinv = 1.f / sm.a.sred[1];
  const int u2 = tid & 127, sh = tid >> 7;
  float cx = 0.f, cy = 0.f;
  for (int s = sh * 84; s < sh * 84 + 84; s++) {
    const float w = sm.a.sc[s] * rinv;
    const float2 ev = __half22float2(*(const __half2*)(E16 + ((ull)b * SS + s) * HH + u2 * 2));
    cx += w * ev.x; cy += w * ev.y;
  }
  sm.a.ctxs[sh * 256 + u2 * 2] = cx;
  sm.a.ctxs[sh * 256 + u2 * 2 + 1] = cy;
  __syncthreads();
  x0[(ull)b * XROW + 1 + tid] = sm.a.ctxs[tid] + sm.a.ctxs[256 + tid];
}

// ---------------------------------------------------------------------------
// One cooperative kernel for the whole network.
// ---------------------------------------------------------------------------
__global__ void seq2seq_fused(
    const float* __restrict__ src,
    const float* __restrict__ ewih0, const float* __restrict__ ewhh0, const float* __restrict__ eb0,
    const float* __restrict__ ewih1, const float* __restrict__ ewhh1, const float* __restrict__ eb1,
    const float* __restrict__ dwih0, const float* __restrict__ dwhh0, const float* __restrict__ db0,
    const float* __restrict__ dwih1, const float* __restrict__ dwhh1, const float* __restrict__ db1,
    const float* __restrict__ attn_w, const float* __restrict__ attn_b, const float* __restrict__ attn_v,
    const float* __restrict__ fc_w, const float* __restrict__ fc_b,
    float* __restrict__ out, float* __restrict__ ws)
{
  cg::grid_group grid = cg::this_grid();
  __shared__ SM sm;
  const int blk = blockIdx.x;
  const int tid = threadIdx.x;

  const ull BH = (ull)BB * HH;
  float* zb     = ws;
  float* c0     = ws + BH;
  float* c1     = ws + 2 * BH;
  float* y0ring = ws + 3 * BH;
  float* h1buf  = ws + 5 * BH;
  float* h0buf  = ws + 7 * BH;
  float* q      = ws + 9 * BH;
  float* x0     = ws + 10 * BH;
  float* wpad   = x0 + (ull)BB * XROW;
  __half* E16   = (__half*)(wpad + (ull)1024 * XROW);
  __half* P16   = E16 + (ull)BB * SS * HH;

  // ---- init: zero zb/c0/c1, x0 col0 + pad, build padded dec_w_ih0 ----
  {
    const int gid = blk * NTHR + tid;
    for (int i = gid; i < 3 * BB * HH; i += NBLK * NTHR) ws[i] = 0.f;
    if (gid < BB) x0[(ull)gid * XROW] = src[(ull)gid * SS * FIN + (SS - 1) * FIN + (FIN - 1)];
    for (int i = gid; i < BB * 31; i += NBLK * NTHR) {
      const int b = i / 31, c = 1 + HH + (i - b * 31);
      x0[(ull)b * XROW + c] = 0.f;
    }
    for (int i = gid; i < 1024 * XROW; i += NBLK * NTHR) {
      const int j = i / XROW, k2 = i - j * XROW;
      wpad[i] = (k2 < HH + 1) ? dwih0[(ull)j * (HH + 1) + k2] : 0.f;
    }
  }
  grid.sync();

  // ---- encoder: diagonal wavefront, layer0[t] + layer1[t-1] per iter ----
  for (int t = 0; t <= SS; t++) {
    if (blk < 128) {
      if (t < SS) {
        const int bt = blk & 15, ut = blk >> 4;
        const float* Hp = (t == 0) ? zb : (y0ring + (ull)((t - 1) & 1) * BH);
        float* Ho = y0ring + (ull)(t & 1) * BH;
        lstm_tile(bt * TB, ut * TU, src + t * FIN, SS * FIN, FIN, ewih0, FIN,
                  Hp, ewhh0, eb0, c0, Ho, nullptr, 0, sm.l.Xs, sm.l.Ws);
      }
    } else {
      const int s = t - 1;
      if (s >= 0) {
        const int b2 = blk - 128;
        const int bt = b2 & 15, ut = b2 >> 4;
        const float* Hp = (s == 0) ? zb : (h1buf + (ull)((s - 1) & 1) * BH);
        float* Ho = h1buf + (ull)(s & 1) * BH;
        const float* Xp = y0ring + (ull)(s & 1) * BH;
        lstm_tile(bt * TB, ut * TU, Xp, HH, HH, ewih1, HH,
                  Hp, ewhh1, eb1, c1, Ho, E16 + (ull)s * HH, (ull)SS * HH, sm.l.Xs, sm.l.Ws);
      }
    }
    grid.sync();
  }

  // ---- enc_proj = enc_out @ We^T, fp16 in/out (5376 tiles, 21 per block) ----
  for (int tile = blk; tile < (BB * SS / 64) * (HH / 64); tile += NBLK)
    gemm_tile<__half, __half>(E16, HH, attn_w, 2 * HH, nullptr, P16, HH, HH,
                              (tile >> 2) * 64, (tile & 3) * 64, sm.g.As, sm.g.Bs);
  grid.sync();

  // ---- decoder ----
  for (int t = 0; t <= TT; t++) {
    const float* h1in = h1buf + (ull)((t + 1) & 1) * BH;  // = h1out(t-1); t=0 -> enc final
    // phase 1: q(t) on blocks 0..31; fc(t-1) on blocks 64..191
    if (t < TT && blk < 32)
      gemm_tile<float, float>(h1in, HH, attn_w + HH, 2 * HH, attn_b, q, HH, HH,
                              (blk & 7) * 64, (blk >> 3) * 64, sm.g.As, sm.g.Bs);
    if (t >= 1 && blk >= 64 && blk < 192) {
      const int gid = (blk - 64) * NTHR + tid;
      const int b = gid >> 6, lane = gid & 63;
      float a = 0.f;
#pragma unroll
      for (int j = 0; j < 4; j++) a += h1in[(ull)b * HH + lane + 64 * j] * fc_w[lane + 64 * j];
#pragma unroll
      for (int m = 32; m >= 1; m >>= 1) a += __shfl_xor(a, m, 64);
      if (lane == 0) {
        const float p = a + fc_b[0];
        out[(ull)b * TT + (t - 1)] = p;
        x0[(ull)b * XROW] = p;
      }
    }
    grid.sync();
    if (t == TT) break;
    // phase 2: attention (2 batch rows per block)
    attn_one(blk, q, P16, E16, attn_v, x0, sm);
    attn_one(blk + 256, q, P16, E16, attn_v, x0, sm);
    grid.sync();
    // phase 3: dec cell0
    const float* h0in = (t == 0) ? (y0ring + BH) : (h0buf + (ull)((t + 1) & 1) * BH);
    float* h0out = h0buf + (ull)(t & 1) * BH;
    if (blk < 128)
      lstm_tile((blk & 15) * TB, (blk >> 4) * TU, x0, XROW, XROW, wpad, XROW,
                h0in, dwhh0, db0, c0, h0out, nullptr, 0, sm.l.Xs, sm.l.Ws);
    grid.sync();
    // phase 4: dec cell1
    float* h1out = h1buf + (ull)(t & 1) * BH;
    if (blk < 128)
      lstm_tile((blk & 15) * TB, (blk >> 4) * TU, h0out, HH, HH, dwih1, HH,
                h1in, dwhh1, db1, c1, h1out, nullptr, 0, sm.l.Xs, sm.l.Ws);
    grid.sync();
  }
}

extern "C" void kernel_launch(void* const* d_in, const int* in_sizes, int n_in,
                              void* d_out, int out_size, void* d_ws, size_t ws_size,
                              hipStream_t stream)
{
  const float* src    = (const float*)d_in[0];
  const float* ewih0  = (const float*)d_in[1];
  const float* ewhh0  = (const float*)d_in[2];
  const float* eb0    = (const float*)d_in[3];
  const float* ewih1  = (const float*)d_in[4];
  const float* ewhh1  = (const float*)d_in[5];
  const float* eb1    = (const float*)d_in[6];
  const float* dwih0  = (const float*)d_in[7];
  const float* dwhh0  = (const float*)d_in[8];
  const float* db0    = (const float*)d_in[9];
  const float* dwih1  = (const float*)d_in[10];
  const float* dwhh1  = (const float*)d_in[11];
  const float* db1    = (const float*)d_in[12];
  const float* attn_w = (const float*)d_in[13];
  const float* attn_b = (const float*)d_in[14];
  const float* attn_v = (const float*)d_in[15];
  // d_in[16] pos_bias: post-tanh, uniform over s -> softmax-invariant, unused.
  const float* fc_w   = (const float*)d_in[17];
  const float* fc_b   = (const float*)d_in[18];
  float* out = (float*)d_out;
  float* ws  = (float*)d_ws;

  void* args[] = {
    (void*)&src,
    (void*)&ewih0, (void*)&ewhh0, (void*)&eb0,
    (void*)&ewih1, (void*)&ewhh1, (void*)&eb1,
    (void*)&dwih0, (void*)&dwhh0, (void*)&db0,
    (void*)&dwih1, (void*)&dwhh1, (void*)&db1,
    (void*)&attn_w, (void*)&attn_b, (void*)&attn_v,
    (void*)&fc_w, (void*)&fc_b,
    (void*)&out, (void*)&ws,
  };
  hipLaunchCooperativeKernel((const void*)seq2seq_fused, dim3(NBLK), dim3(NTHR),
                             args, 0, stream);
}

// Round 3
// 23814.211 us; speedup vs baseline: 1.1369x; 1.1369x over previous
//
#include <hip/hip_runtime.h>
#include <hip/hip_fp16.h>
#include <math.h>

#define BB 512
#define HH 256
#define SS 168
#define TT 24
#define FIN 16
#define KC 32
#define TB 32
#define TU 32
#define XROW 288   // padded x0 row / padded dec_w_ih0 row (257 -> 288, zero-filled)
#define NBLK 256
#define NTHR 256

typedef unsigned long long ull;

__device__ __forceinline__ float sigf(float x) { return 1.f / (1.f + expf(-x)); }

struct SM {
  union {
    struct { float Xs[KC][TB + 1]; float Ws[KC][4 * TU + 4]; } l;  // 21120 B
    struct { float As[KC][65]; float Bs[KC][65]; } g;              // 16640 B
    struct { float qs[256], vs[256], sc[192], ctxs[512], sred[2]; } a;
  };
};

// ---------------------------------------------------------------------------
// Custom grid barrier: per-block release flag + leader broadcast.
// bar[0..255] = per-block flags, bar[384] = generation. ~3-5us vs ~90us for
// cg::grid.sync() (R2 measured: VALUBusy 6.8%, ~90us/sync in sleep backoff).
// ---------------------------------------------------------------------------
__device__ __forceinline__ void gbar(int* __restrict__ bar, int it)
{
  __syncthreads();
  if (blockIdx.x == 0) {
    if (threadIdx.x > 0) {
      while (__hip_atomic_load(bar + threadIdx.x, __ATOMIC_RELAXED,
                               __HIP_MEMORY_SCOPE_AGENT) < it) {
        __builtin_amdgcn_s_sleep(1);
      }
    }
    __threadfence();  // acquire: all blocks' prior writes visible
    __syncthreads();
    if (threadIdx.x == 0)
      __hip_atomic_store(bar + 384, it, __ATOMIC_RELEASE, __HIP_MEMORY_SCOPE_AGENT);
  } else {
    if (threadIdx.x == 0) {
      __hip_atomic_store(bar + blockIdx.x, it, __ATOMIC_RELEASE, __HIP_MEMORY_SCOPE_AGENT);
      while (__hip_atomic_load(bar + 384, __ATOMIC_RELAXED,
                               __HIP_MEMORY_SCOPE_AGENT) < it) {
        __builtin_amdgcn_s_sleep(1);
      }
    }
    __syncthreads();
    __threadfence();  // acquire side for all lanes before touching shared data
  }
}

__global__ void init_bar(int* bar) { bar[blockIdx.x * 256 + threadIdx.x] = 0; }

// ---------------------------------------------------------------------------
// Fused LSTM step tile: gates = bias + X@Wih^T + Hprev@Whh^T, then pointwise.
// Block tile 32b x 32u (128 gate cols); 256 thr: bq=tid&7 (4 b), ul=tid>>3.
// ---------------------------------------------------------------------------
__device__ void lstm_tile(
    int b0, int u0,
    const float* __restrict__ X, int rsX, int KIN,
    const float* __restrict__ Wih, int rsWih,
    const float* __restrict__ Hprev,
    const float* __restrict__ Whh,
    const float* __restrict__ bias,
    float* __restrict__ C, float* __restrict__ Hout,
    __half* __restrict__ E16out, ull eStrideB,
    float (*Xs)[TB + 1], float (*Ws)[4 * TU + 4])
{
  const int tid = threadIdx.x;
  const int bq = tid & 7;
  const int ul = tid >> 3;
  const int u = u0 + ul;

  float acc[4][4];
#pragma unroll
  for (int g = 0; g < 4; g++) {
    const float bv = bias[g * HH + u];
    acc[0][g] = bv; acc[1][g] = bv; acc[2][g] = bv; acc[3][g] = bv;
  }

#pragma unroll
  for (int ph = 0; ph < 2; ph++) {
    const float* A = ph ? Hprev : X;
    const float* W = ph ? Whh : Wih;
    const int rsA = ph ? HH : rsX;
    const int rsW = ph ? HH : rsWih;
    const int K = ph ? HH : KIN;
    for (int k0 = 0; k0 < K; k0 += KC) {
      const int kc = (KC < K - k0) ? KC : (K - k0);
      if (kc == KC && (rsA & 3) == 0) {
        const int bi = tid & 31, kq = tid >> 5;
        const float4 v = *(const float4*)(A + (ull)(b0 + bi) * rsA + k0 + kq * 4);
        Xs[kq * 4 + 0][bi] = v.x; Xs[kq * 4 + 1][bi] = v.y;
        Xs[kq * 4 + 2][bi] = v.z; Xs[kq * 4 + 3][bi] = v.w;
      } else {
        for (int idx = tid; idx < kc * 32; idx += 256) {
          const int bi = idx & 31, kk = idx >> 5;
          Xs[kk][bi] = A[(ull)(b0 + bi) * rsA + k0 + kk];
        }
      }
      if (kc == KC && (rsW & 3) == 0) {
        const int cl = tid & 127, kq = tid >> 7;
        const int j = (cl & 3) * HH + u0 + (cl >> 2);
        const float* gw = W + (ull)j * rsW + k0 + kq * 16;
#pragma unroll
        for (int i = 0; i < 4; i++) {
          const float4 v = *(const float4*)(gw + i * 4);
          const int kk = kq * 16 + i * 4;
          Ws[kk + 0][cl] = v.x; Ws[kk + 1][cl] = v.y;
          Ws[kk + 2][cl] = v.z; Ws[kk + 3][cl] = v.w;
        }
      } else {
        for (int idx = tid; idx < kc * 128; idx += 256) {
          const int cl = idx & 127, kk = idx >> 7;
          const int j = (cl & 3) * HH + u0 + (cl >> 2);
          Ws[kk][cl] = W[(ull)j * rsW + k0 + kk];
        }
      }
      __syncthreads();
      if (kc == KC) {
#pragma unroll 8
        for (int kk = 0; kk < KC; kk++) {
          const float4 xv = *(const float4*)&Xs[kk][bq * 4];
          const float4 wv = *(const float4*)&Ws[kk][ul * 4];
          acc[0][0] += xv.x * wv.x; acc[0][1] += xv.x * wv.y; acc[0][2] += xv.x * wv.z; acc[0][3] += xv.x * wv.w;
          acc[1][0] += xv.y * wv.x; acc[1][1] += xv.y * wv.y; acc[1][2] += xv.y * wv.z; acc[1][3] += xv.y * wv.w;
          acc[2][0] += xv.z * wv.x; acc[2][1] += xv.z * wv.y; acc[2][2] += xv.z * wv.z; acc[2][3] += xv.z * wv.w;
          acc[3][0] += xv.w * wv.x; acc[3][1] += xv.w * wv.y; acc[3][2] += xv.w * wv.z; acc[3][3] += xv.w * wv.w;
        }
      } else {
        for (int kk = 0; kk < kc; kk++) {
          const float4 xv = *(const float4*)&Xs[kk][bq * 4];
          const float4 wv = *(const float4*)&Ws[kk][ul * 4];
          acc[0][0] += xv.x * wv.x; acc[0][1] += xv.x * wv.y; acc[0][2] += xv.x * wv.z; acc[0][3] += xv.x * wv.w;
          acc[1][0] += xv.y * wv.x; acc[1][1] += xv.y * wv.y; acc[1][2] += xv.y * wv.z; acc[1][3] += xv.y * wv.w;
          acc[2][0] += xv.z * wv.x; acc[2][1] += xv.z * wv.y; acc[2][2] += xv.z * wv.z; acc[2][3] += xv.z * wv.w;
          acc[3][0] += xv.w * wv.x; acc[3][1] += xv.w * wv.y; acc[3][2] += xv.w * wv.z; acc[3][3] += xv.w * wv.w;
        }
      }
      __syncthreads();
    }
  }
#pragma unroll
  for (int bd = 0; bd < 4; bd++) {
    const int b = b0 + bq * 4 + bd;
    const float iv = sigf(acc[bd][0]);
    const float fv = sigf(acc[bd][1]);
    const float gv = tanhf(acc[bd][2]);
    const float ov = sigf(acc[bd][3]);
    const ull ci = (ull)b * HH + u;
    const float cn = fv * C[ci] + iv * gv;
    C[ci] = cn;
    const float hn = ov * tanhf(cn);
    Hout[ci] = hn;
    if (E16out) E16out[(ull)b * eStrideB + u] = __float2half(hn);
  }
}

// ---------------------------------------------------------------------------
// Generic 64x64 gemm tile: C[m][n] = bias[n] + sum_k A[m][k]*Bw[n][k]
// ---------------------------------------------------------------------------
template <typename AT, typename CT>
__device__ void gemm_tile(
    const AT* __restrict__ A, int rsA,
    const float* __restrict__ Bw, int rsB,
    const float* __restrict__ bias,
    CT* __restrict__ Cout, int rsC, int K, int m0, int n0,
    float (*As)[65], float (*Bs)[65])
{
  const int tid = threadIdx.x;
  const int mq = tid & 15, nq = tid >> 4;
  const int li = tid & 63, kq = tid >> 6;
  float acc[4][4] = {{0.f}};
  for (int k0 = 0; k0 < K; k0 += KC) {
    if constexpr (sizeof(AT) == 2) {
      float4 raw = *(const float4*)(A + (ull)(m0 + li) * rsA + k0 + kq * 8);
      const __half* hp = (const __half*)&raw;
#pragma unroll
      for (int i = 0; i < 8; i++) As[kq * 8 + i][li] = __half2float(hp[i]);
    } else {
      const float* ga = (const float*)A + (ull)(m0 + li) * rsA + k0 + kq * 8;
      const float4 v0 = *(const float4*)ga, v1 = *(const float4*)(ga + 4);
      As[kq * 8 + 0][li] = v0.x; As[kq * 8 + 1][li] = v0.y; As[kq * 8 + 2][li] = v0.z; As[kq * 8 + 3][li] = v0.w;
      As[kq * 8 + 4][li] = v1.x; As[kq * 8 + 5][li] = v1.y; As[kq * 8 + 6][li] = v1.z; As[kq * 8 + 7][li] = v1.w;
    }
    {
      const float* gb = Bw + (ull)(n0 + li) * rsB + k0 + kq * 8;
      const float4 v0 = *(const float4*)gb, v1 = *(const float4*)(gb + 4);
      Bs[kq * 8 + 0][li] = v0.x; Bs[kq * 8 + 1][li] = v0.y; Bs[kq * 8 + 2][li] = v0.z; Bs[kq * 8 + 3][li] = v0.w;
      Bs[kq * 8 + 4][li] = v1.x; Bs[kq * 8 + 5][li] = v1.y; Bs[kq * 8 + 6][li] = v1.z; Bs[kq * 8 + 7][li] = v1.w;
    }
    __syncthreads();
#pragma unroll 8
    for (int kk = 0; kk < KC; kk++) {
      const float4 a4 = *(const float4*)&As[kk][mq * 4];
      const float4 b4 = *(const float4*)&Bs[kk][nq * 4];
      acc[0][0] += a4.x * b4.x; acc[0][1] += a4.x * b4.y; acc[0][2] += a4.x * b4.z; acc[0][3] += a4.x * b4.w;
      acc[1][0] += a4.y * b4.x; acc[1][1] += a4.y * b4.y; acc[1][2] += a4.y * b4.z; acc[1][3] += a4.y * b4.w;
      acc[2][0] += a4.z * b4.x; acc[2][1] += a4.z * b4.y; acc[2][2] += a4.z * b4.z; acc[2][3] += a4.z * b4.w;
      acc[3][0] += a4.w * b4.x; acc[3][1] += a4.w * b4.y; acc[3][2] += a4.w * b4.z; acc[3][3] += a4.w * b4.w;
    }
    __syncthreads();
  }
#pragma unroll
  for (int i = 0; i < 4; i++) {
    const int m = m0 + mq * 4 + i;
    float r[4];
#pragma unroll
    for (int j = 0; j < 4; j++) r[j] = acc[i][j] + (bias ? bias[n0 + nq * 4 + j] : 0.f);
    if constexpr (sizeof(CT) == 2) {
      __half2* p = (__half2*)((__half*)Cout + (ull)m * rsC + n0 + nq * 4);
      __half2 h0; h0.x = __float2half(r[0]); h0.y = __float2half(r[1]);
      __half2 h1; h1.x = __float2half(r[2]); h1.y = __float2half(r[3]);
      p[0] = h0; p[1] = h1;
    } else {
      float4 v; v.x = r[0]; v.y = r[1]; v.z = r[2]; v.w = r[3];
      *(float4*)((float*)Cout + (ull)m * rsC + n0 + nq * 4) = v;
    }
  }
}

// ---------------------------------------------------------------------------
// Decoder phase A for one batch row b: fc(t-1) (pred -> out, dec_in), then
// q = h1 @ Wd^T + attn_b (in-LDS, WdT pre-transposed), then attention ->
// ctx into x0[b][1..256]. pos_bias omitted (softmax-invariant).
// ---------------------------------------------------------------------------
__device__ void decA(int b, int t, const float* __restrict__ h1in,
                     const float* __restrict__ wdT,
                     const float* __restrict__ attn_b, const float* __restrict__ attn_v,
                     const __half* __restrict__ P16, const __half* __restrict__ E16,
                     const float* __restrict__ fc_w, const float* __restrict__ fc_b,
                     float* __restrict__ x0, float* __restrict__ out, SM& sm)
{
  const int tid = threadIdx.x;
  __syncthreads();   // protect LDS union reuse
  sm.a.ctxs[tid] = h1in[(ull)b * HH + tid];   // stage h1 row b
  __syncthreads();
  if (t >= 1 && tid < 64) {                   // fc for step t-1
    float a = 0.f;
#pragma unroll
    for (int j = 0; j < 4; j++) a += sm.a.ctxs[tid + 64 * j] * fc_w[tid + 64 * j];
#pragma unroll
    for (int m = 32; m >= 1; m >>= 1) a += __shfl_xor(a, m, 64);
    if (tid == 0) {
      const float p = a + fc_b[0];
      out[(ull)b * TT + (t - 1)] = p;
      x0[(ull)b * XROW] = p;
    }
  }
  if (t >= TT) return;
  // q[g=tid] = attn_b[g] + sum_k h1row[k] * WdT[k][g]  (coalesced, LDS bcast)
  float qv = attn_b[tid];
  for (int k = 0; k < HH; k += 4) {
    qv += sm.a.ctxs[k]     * wdT[(ull)(k)     * HH + tid];
    qv += sm.a.ctxs[k + 1] * wdT[(ull)(k + 1) * HH + tid];
    qv += sm.a.ctxs[k + 2] * wdT[(ull)(k + 2) * HH + tid];
    qv += sm.a.ctxs[k + 3] * wdT[(ull)(k + 3) * HH + tid];
  }
  __syncthreads();
  sm.a.qs[tid] = qv;
  sm.a.vs[tid] = attn_v[tid];
  __syncthreads();
  const int wv = tid >> 6, lane = tid & 63;
  for (int s = wv; s < SS; s += 4) {
    const __half2* Pr = (const __half2*)(P16 + ((ull)b * SS + s) * HH);
    float a = 0.f;
#pragma unroll
    for (int jj = 0; jj < 2; jj++) {
      const int i2 = lane + 64 * jj;
      const float2 pv = __half22float2(Pr[i2]);
      const int g0 = i2 * 2;
      a += sm.a.vs[g0] * tanhf(pv.x + sm.a.qs[g0]);
      a += sm.a.vs[g0 + 1] * tanhf(pv.y + sm.a.qs[g0 + 1]);
    }
#pragma unroll
    for (int m = 32; m >= 1; m >>= 1) a += __shfl_xor(a, m, 64);
    if (lane == 0) sm.a.sc[s] = a;
  }
  __syncthreads();
  if (tid < 64) {
    float m = -1e30f;
    for (int i = tid; i < SS; i += 64) m = fmaxf(m, sm.a.sc[i]);
#pragma unroll
    for (int mm = 32; mm >= 1; mm >>= 1) m = fmaxf(m, __shfl_xor(m, mm, 64));
    if (tid == 0) sm.a.sred[0] = m;
  }
  __syncthreads();
  const float smax = sm.a.sred[0];
  if (tid < SS) sm.a.sc[tid] = expf(sm.a.sc[tid] - smax);
  __syncthreads();
  if (tid < 64) {
    float ssum = 0.f;
    for (int i = tid; i < SS; i += 64) ssum += sm.a.sc[i];
#pragma unroll
    for (int mm = 32; mm >= 1; mm >>= 1) ssum += __shfl_xor(ssum, mm, 64);
    if (tid == 0) sm.a.sred[1] = ssum;
  }
  __syncthreads();
  const float rinv = 1.f / sm.a.sred[1];
  const int u2 = tid & 127, sh = tid >> 7;
  float cx = 0.f, cy = 0.f;
  for (int s = sh * 84; s < sh * 84 + 84; s++) {
    const float w = sm.a.sc[s] * rinv;
    const float2 ev = __half22float2(*(const __half2*)(E16 + ((ull)b * SS + s) * HH + u2 * 2));
    cx += w * ev.x; cy += w * ev.y;
  }
  sm.a.ctxs[sh * 256 + u2 * 2] = cx;
  sm.a.ctxs[sh * 256 + u2 * 2 + 1] = cy;
  __syncthreads();
  x0[(ull)b * XROW + 1 + tid] = sm.a.ctxs[tid] + sm.a.ctxs[256 + tid];
}

// ---------------------------------------------------------------------------
// One cooperative kernel for the whole network, custom barrier.
// ---------------------------------------------------------------------------
__global__ void seq2seq_fused(
    const float* __restrict__ src,
    const float* __restrict__ ewih0, const float* __restrict__ ewhh0, const float* __restrict__ eb0,
    const float* __restrict__ ewih1, const float* __restrict__ ewhh1, const float* __restrict__ eb1,
    const float* __restrict__ dwih0, const float* __restrict__ dwhh0, const float* __restrict__ db0,
    const float* __restrict__ dwih1, const float* __restrict__ dwhh1, const float* __restrict__ db1,
    const float* __restrict__ attn_w, const float* __restrict__ attn_b, const float* __restrict__ attn_v,
    const float* __restrict__ fc_w, const float* __restrict__ fc_b,
    float* __restrict__ out, int* __restrict__ bar)
{
  __shared__ SM sm;
  const int blk = blockIdx.x;
  const int tid = threadIdx.x;
  int it = 0;

  const ull BH = (ull)BB * HH;
  float* f      = (float*)(bar + 512);
  float* zb     = f;
  float* c0     = f + BH;
  float* c1     = f + 2 * BH;
  float* y0ring = f + 3 * BH;
  float* h1buf  = f + 5 * BH;
  float* h0buf  = f + 7 * BH;
  float* x0     = f + 9 * BH;
  float* wpad   = x0 + (ull)BB * XROW;
  float* wdT    = wpad + (ull)1024 * XROW;
  __half* E16   = (__half*)(wdT + (ull)HH * HH);
  __half* P16   = E16 + (ull)BB * SS * HH;

  // ---- init: zero zb/c0/c1, x0 col0+pad, padded dec_w_ih0, WdT ----
  {
    const int gid = blk * NTHR + tid;
    for (int i = gid; i < 3 * BB * HH; i += NBLK * NTHR) f[i] = 0.f;
    if (gid < BB) x0[(ull)gid * XROW] = src[(ull)gid * SS * FIN + (SS - 1) * FIN + (FIN - 1)];
    for (int i = gid; i < BB * 31; i += NBLK * NTHR) {
      const int b = i / 31, c = 1 + HH + (i - b * 31);
      x0[(ull)b * XROW + c] = 0.f;
    }
    for (int i = gid; i < 1024 * XROW; i += NBLK * NTHR) {
      const int j = i / XROW, k2 = i - j * XROW;
      wpad[i] = (k2 < HH + 1) ? dwih0[(ull)j * (HH + 1) + k2] : 0.f;
    }
    for (int i = gid; i < HH * HH; i += NBLK * NTHR) {
      const int k2 = i >> 8, g = i & 255;
      wdT[i] = attn_w[(ull)g * 2 * HH + HH + k2];
    }
  }
  gbar(bar, ++it);

  // ---- encoder: diagonal wavefront, layer0[t] + layer1[t-1] per iter ----
  for (int t = 0; t <= SS; t++) {
    if (blk < 128) {
      if (t < SS) {
        const int bt = blk & 15, ut = blk >> 4;
        const float* Hp = (t == 0) ? zb : (y0ring + (ull)((t - 1) & 1) * BH);
        float* Ho = y0ring + (ull)(t & 1) * BH;
        lstm_tile(bt * TB, ut * TU, src + t * FIN, SS * FIN, FIN, ewih0, FIN,
                  Hp, ewhh0, eb0, c0, Ho, nullptr, 0, sm.l.Xs, sm.l.Ws);
      }
    } else {
      const int s = t - 1;
      if (s >= 0) {
        const int b2 = blk - 128;
        const int bt = b2 & 15, ut = b2 >> 4;
        const float* Hp = (s == 0) ? zb : (h1buf + (ull)((s - 1) & 1) * BH);
        float* Ho = h1buf + (ull)(s & 1) * BH;
        const float* Xp = y0ring + (ull)(s & 1) * BH;
        lstm_tile(bt * TB, ut * TU, Xp, HH, HH, ewih1, HH,
                  Hp, ewhh1, eb1, c1, Ho, E16 + (ull)s * HH, (ull)SS * HH, sm.l.Xs, sm.l.Ws);
      }
    }
    gbar(bar, ++it);
  }

  // ---- enc_proj = enc_out @ We^T, fp16 in/out (5376 tiles, 21 per block) ----
  for (int tile = blk; tile < (BB * SS / 64) * (HH / 64); tile += NBLK)
    gemm_tile<__half, __half>(E16, HH, attn_w, 2 * HH, nullptr, P16, HH, HH,
                              (tile >> 2) * 64, (tile & 3) * 64, sm.g.As, sm.g.Bs);
  gbar(bar, ++it);

  // ---- decoder: 3 barriers per step ----
  for (int t = 0; t <= TT; t++) {
    const float* h1in = h1buf + (ull)((t + 1) & 1) * BH;  // h1(t-1); t=0 -> enc final
    decA(blk,       t, h1in, wdT, attn_b, attn_v, P16, E16, fc_w, fc_b, x0, out, sm);
    decA(blk + 256, t, h1in, wdT, attn_b, attn_v, P16, E16, fc_w, fc_b, x0, out, sm);
    gbar(bar, ++it);
    if (t == TT) break;
    const float* h0in = (t == 0) ? (y0ring + BH) : (h0buf + (ull)((t + 1) & 1) * BH);
    float* h0out = h0buf + (ull)(t & 1) * BH;
    if (blk < 128)
      lstm_tile((blk & 15) * TB, (blk >> 4) * TU, x0, XROW, XROW, wpad, XROW,
                h0in, dwhh0, db0, c0, h0out, nullptr, 0, sm.l.Xs, sm.l.Ws);
    gbar(bar, ++it);
    float* h1out = h1buf + (ull)(t & 1) * BH;
    if (blk < 128)
      lstm_tile((blk & 15) * TB, (blk >> 4) * TU, h0out, HH, HH, dwih1, HH,
                h1in, dwhh1, db1, c1, h1out, nullptr, 0, sm.l.Xs, sm.l.Ws);
    gbar(bar, ++it);
  }
}

extern "C" void kernel_launch(void* const* d_in, const int* in_sizes, int n_in,
                              void* d_out, int out_size, void* d_ws, size_t ws_size,
                              hipStream_t stream)
{
  const float* src    = (const float*)d_in[0];
  const float* ewih0  = (const float*)d_in[1];
  const float* ewhh0  = (const float*)d_in[2];
  const float* eb0    = (const float*)d_in[3];
  const float* ewih1  = (const float*)d_in[4];
  const float* ewhh1  = (const float*)d_in[5];
  const float* eb1    = (const float*)d_in[6];
  const float* dwih0  = (const float*)d_in[7];
  const float* dwhh0  = (const float*)d_in[8];
  const float* db0    = (const float*)d_in[9];
  const float* dwih1  = (const float*)d_in[10];
  const float* dwhh1  = (const float*)d_in[11];
  const float* db1    = (const float*)d_in[12];
  const float* attn_w = (const float*)d_in[13];
  const float* attn_b = (const float*)d_in[14];
  const float* attn_v = (const float*)d_in[15];
  // d_in[16] pos_bias: post-tanh, uniform over s -> softmax-invariant, unused.
  const float* fc_w   = (const float*)d_in[17];
  const float* fc_b   = (const float*)d_in[18];
  float* out = (float*)d_out;
  int* bar   = (int*)d_ws;

  init_bar<<<2, 256, 0, stream>>>(bar);

  void* args[] = {
    (void*)&src,
    (void*)&ewih0, (void*)&ewhh0, (void*)&eb0,
    (void*)&ewih1, (void*)&ewhh1, (void*)&eb1,
    (void*)&dwih0, (void*)&dwhh0, (void*)&db0,
    (void*)&dwih1, (void*)&dwhh1, (void*)&db1,
    (void*)&attn_w, (void*)&attn_b, (void*)&attn_v,
    (void*)&fc_w, (void*)&fc_b,
    (void*)&out, (void*)&bar,
  };
  hipLaunchCooperativeKernel((const void*)seq2seq_fused, dim3(NBLK), dim3(NTHR),
                             args, 0, stream);
}

// Round 5
// 11987.122 us; speedup vs baseline: 2.2586x; 1.9866x over previous
//
#include <hip/hip_runtime.h>
#include <hip/hip_fp16.h>
#include <math.h>

#define BB 512
#define HH 256
#define SS 168
#define TT 24
#define NBLK 256
#define NTHR 256
typedef unsigned long long ull;
#define BH 131072ull  // 512*256

// ---- int flag offsets (ints from ws) ----
#define IF0 0       // [t*16+bt0] target 8
#define IF1 4096    // [s*8+bt1] target 16
#define IFA 6144    // [t*16+g32] target 16
#define IFH0 6656   // [t*16+bt0] target 8
#define IFH1 7168   // [t*8+bt1] target 16
#define IFP 7680    // target 256
// ---- float offsets from fb = (float*)ws + 65536 ----
#define O_Y0  0ull        // y0 ring, 4 slots (4*BH)
#define O_H1  524288ull   // h1 ring, 2 slots
#define O_H0  786432ull   // dec h0 ring, 2 slots
#define O_CTX 1048576ull  // 512 x 288 (cols 0..255 ctx, col 256 pred)
#define O_WT0 1196032ull  // enc l0 W^T [272][1024]
#define O_WT1 1474560ull  // enc l1 W^T [512][1024]
#define O_WD0 1998848ull  // dec c0 W^T [513][1024]
#define O_WD1 2524160ull  // dec c1 W^T [512][1024]
#define O_WDT 3048448ull  // Wd^T [256][256]
#define O_BP  3113984ull  // packed biases 4x1024 (e0,e1,d0,d1)
#define O_E16 3118080ull  // half[512][168][256]
#define O_P16 14128128ull // half[512][168][256]

__device__ __forceinline__ float sigf(float x) { return 1.f / (1.f + expf(-x)); }

// ---- coherent (L3-point) transport: relaxed agent-scope atomics, no fences ----
__device__ __forceinline__ float2 ld2(const float* p) {
  ull raw = __hip_atomic_load((const ull*)p, __ATOMIC_RELAXED, __HIP_MEMORY_SCOPE_AGENT);
  float2 v; v.x = __uint_as_float((unsigned)raw); v.y = __uint_as_float((unsigned)(raw >> 32));
  return v;
}
__device__ __forceinline__ float ld1(const float* p) {
  unsigned raw = __hip_atomic_load((const unsigned*)p, __ATOMIC_RELAXED, __HIP_MEMORY_SCOPE_AGENT);
  return __uint_as_float(raw);
}
__device__ __forceinline__ void st1(float* p, float v) {
  __hip_atomic_store((unsigned*)p, __float_as_uint(v), __ATOMIC_RELAXED, __HIP_MEMORY_SCOPE_AGENT);
}
__device__ __forceinline__ void sth(__half* p, __half v) {
  __hip_atomic_store((unsigned short*)p, __half_as_ushort(v), __ATOMIC_RELAXED, __HIP_MEMORY_SCOPE_AGENT);
}
__device__ __forceinline__ void stu(unsigned* p, unsigned v) {
  __hip_atomic_store(p, v, __ATOMIC_RELAXED, __HIP_MEMORY_SCOPE_AGENT);
}

// ---- flag sync: no fences; data already at coherence point before arrive ----
__device__ __forceinline__ void poll(int* f, int tgt) {
  while (__hip_atomic_load(f, __ATOMIC_RELAXED, __HIP_MEMORY_SCOPE_AGENT) < tgt)
    __builtin_amdgcn_s_sleep(1);
}
__device__ __forceinline__ void flag_arrive(int* f) {
  asm volatile("s_waitcnt vmcnt(0)" ::: "memory");  // all bypass stores acked at L3
  __syncthreads();                                   // every wave drained
  if (threadIdx.x == 0)
    __hip_atomic_fetch_add(f, 1, __ATOMIC_RELAXED, __HIP_MEMORY_SCOPE_AGENT);
}
__device__ __forceinline__ void flag_wait3(int* f0, int t0, int* f1, int t1, int* f2, int t2) {
  if (threadIdx.x == 0 && f0) poll(f0, t0);
  if (threadIdx.x == 64 && f1) poll(f1, t1);
  if (threadIdx.x == 128 && f2) poll(f2, t2);
  __syncthreads();
}

// ---- LDS ----
struct SMT {
  union {
    struct { float Ws[32][132]; float Hs[32][36]; } a;   // 32rows x 128gc tiles
    struct { float Ws[32][68];  float Hs[32][68]; } b;   // 64rows x 64gc tiles
    struct { float As[32][65];  float Bs[32][65]; } g;   // enc_proj gemm
    struct { float h1s[256], qs[256], vs[256], sc[192], ctxs[512], sred[4]; } at;
  };
};

// ---- staging (W from pre-transposed wT via cached loads; H via bypass) ----
__device__ __forceinline__ void stage_W128(const float* wTk, int gc0, float Ws[32][132]) {
  const int tid = threadIdx.x, gcq = tid & 31, kk4 = tid >> 5;
#pragma unroll
  for (int i = 0; i < 4; i++) {
    const int kk = kk4 * 4 + i;
    *(float4*)&Ws[kk][gcq * 4] = *(const float4*)(wTk + (ull)kk * 1024 + gc0 + gcq * 4);
  }
}
__device__ __forceinline__ void stage_W128h(const float* wTk, int gc0, float Ws[32][132]) { // 16 kk
  const int tid = threadIdx.x, gcq = tid & 31, kk2 = tid >> 5;
#pragma unroll
  for (int i = 0; i < 2; i++) {
    const int kk = kk2 * 2 + i;
    *(float4*)&Ws[kk][gcq * 4] = *(const float4*)(wTk + (ull)kk * 1024 + gc0 + gcq * 4);
  }
}
__device__ __forceinline__ void stage_W64(const float* wTk, int gc0, float Ws[32][68]) {
  const int tid = threadIdx.x, gcq = tid & 15, kk2 = tid >> 4;
#pragma unroll
  for (int i = 0; i < 2; i++) {
    const int kk = kk2 * 2 + i;
    *(float4*)&Ws[kk][gcq * 4] = *(const float4*)(wTk + (ull)kk * 1024 + gc0 + gcq * 4);
  }
}
__device__ __forceinline__ void stage_H32(const float* h, ull rstride, int row0, int k0,
                                          int zero, float Hs[32][36]) {
  const int tid = threadIdx.x, r = tid & 31, p = tid >> 5;
#pragma unroll
  for (int j = 0; j < 2; j++) {
    const int pp = p + j * 8;
    float2 v = {0.f, 0.f};
    if (!zero) v = ld2(h + (ull)(row0 + r) * rstride + k0 + pp * 2);
    Hs[pp * 2 + 0][r] = v.x; Hs[pp * 2 + 1][r] = v.y;
  }
}
__device__ __forceinline__ void stage_H64(const float* h, int row0, int k0,
                                          int zero, float Hs[32][68]) {
  const int tid = threadIdx.x, r = tid & 63, p = tid >> 6;
#pragma unroll
  for (int j = 0; j < 4; j++) {
    const int pp = p + j * 4;
    float2 v = {0.f, 0.f};
    if (!zero) v = ld2(h + (ull)(row0 + r) * 256 + k0 + pp * 2);
    Hs[pp * 2 + 0][r] = v.x; Hs[pp * 2 + 1][r] = v.y;
  }
}

__device__ __forceinline__ void fma16(float acc[4][4], const float4 hv, const float4 wv) {
  acc[0][0] += hv.x * wv.x; acc[0][1] += hv.x * wv.y; acc[0][2] += hv.x * wv.z; acc[0][3] += hv.x * wv.w;
  acc[1][0] += hv.y * wv.x; acc[1][1] += hv.y * wv.y; acc[1][2] += hv.y * wv.z; acc[1][3] += hv.y * wv.w;
  acc[2][0] += hv.z * wv.x; acc[2][1] += hv.z * wv.y; acc[2][2] += hv.z * wv.z; acc[2][3] += hv.z * wv.w;
  acc[3][0] += hv.w * wv.x; acc[3][1] += hv.w * wv.y; acc[3][2] += hv.w * wv.z; acc[3][3] += hv.w * wv.w;
}
__device__ __forceinline__ void comp128(float Ws[32][132], float Hs[32][36], int bq, int ul,
                                        float acc[4][4], int nkk) {
#pragma unroll 8
  for (int kk = 0; kk < nkk; kk++)
    fma16(acc, *(const float4*)&Hs[kk][bq * 4], *(const float4*)&Ws[kk][ul * 4]);
}
__device__ __forceinline__ void comp64(float Ws[32][68], float Hs[32][68], int rq, int ul,
                                       float acc[4][4]) {
#pragma unroll 8
  for (int kk = 0; kk < 32; kk++)
    fma16(acc, *(const float4*)&Hs[kk][rq * 4], *(const float4*)&Ws[kk][ul * 4]);
}

// ---- attention + fc for one batch row ----
__device__ void attn_fc(int row, int t, int slot, const float* h1r, const float* wdT,
                        const float* attn_b, const float* attn_v,
                        const __half* P16, const __half* E16,
                        const float* fc_w, const float* fc_b,
                        float* ctxb, float* out, SMT& sm)
{
  const int tid = threadIdx.x;
  __syncthreads();
  if (tid < 128) {
    float2 v = ld2(h1r + slot * BH + (ull)row * 256 + tid * 2);
    sm.at.h1s[tid * 2] = v.x; sm.at.h1s[tid * 2 + 1] = v.y;
  }
  __syncthreads();
  if (t >= 1 && tid < 64) {
    float a = 0.f;
#pragma unroll
    for (int j = 0; j < 4; j++) a += sm.at.h1s[tid + 64 * j] * fc_w[tid + 64 * j];
#pragma unroll
    for (int m = 32; m >= 1; m >>= 1) a += __shfl_xor(a, m, 64);
    if (tid == 0) {
      const float p = a + fc_b[0];
      out[(ull)row * TT + (t - 1)] = p;
      st1(ctxb + (ull)row * 288 + 256, p);
    }
  }
  if (t >= TT) return;
  float qv = attn_b[tid];
  for (int k = 0; k < 256; k += 4) {
    qv += sm.at.h1s[k]     * wdT[(ull)(k)     * 256 + tid];
    qv += sm.at.h1s[k + 1] * wdT[(ull)(k + 1) * 256 + tid];
    qv += sm.at.h1s[k + 2] * wdT[(ull)(k + 2) * 256 + tid];
    qv += sm.at.h1s[k + 3] * wdT[(ull)(k + 3) * 256 + tid];
  }
  sm.at.qs[tid] = qv;
  sm.at.vs[tid] = attn_v[tid];
  __syncthreads();
  const int wv = tid >> 6, lane = tid & 63;
  for (int s = wv; s < SS; s += 4) {
    const __half2* Pr = (const __half2*)(P16 + ((ull)row * SS + s) * 256);
    float a = 0.f;
#pragma unroll
    for (int jj = 0; jj < 2; jj++) {
      const int i2 = lane + 64 * jj;
      const float2 pv = __half22float2(Pr[i2]);
      const int g0 = i2 * 2;
      a += sm.at.vs[g0] * tanhf(pv.x + sm.at.qs[g0]);
      a += sm.at.vs[g0 + 1] * tanhf(pv.y + sm.at.qs[g0 + 1]);
    }
#pragma unroll
    for (int m = 32; m >= 1; m >>= 1) a += __shfl_xor(a, m, 64);
    if (lane == 0) sm.at.sc[s] = a;
  }
  __syncthreads();
  if (tid < 64) {
    float m = -1e30f;
    for (int i = tid; i < SS; i += 64) m = fmaxf(m, sm.at.sc[i]);
#pragma unroll
    for (int mm = 32; mm >= 1; mm >>= 1) m = fmaxf(m, __shfl_xor(m, mm, 64));
    if (tid == 0) sm.at.sred[0] = m;
  }
  __syncthreads();
  const float smax = sm.at.sred[0];
  if (tid < SS) sm.at.sc[tid] = expf(sm.at.sc[tid] - smax);
  __syncthreads();
  if (tid < 64) {
    float ssum = 0.f;
    for (int i = tid; i < SS; i += 64) ssum += sm.at.sc[i];
#pragma unroll
    for (int mm = 32; mm >= 1; mm >>= 1) ssum += __shfl_xor(ssum, mm, 64);
    if (tid == 0) sm.at.sred[1] = ssum;
  }
  __syncthreads();
  const float rinv = 1.f / sm.at.sred[1];
  const int u2 = tid & 127, sh = tid >> 7;
  float cx = 0.f, cy = 0.f;
  for (int s = sh * 84; s < sh * 84 + 84; s++) {
    const float w = sm.at.sc[s] * rinv;
    const float2 ev = __half22float2(*(const __half2*)(E16 + ((ull)row * SS + s) * 256 + u2 * 2));
    cx += w * ev.x; cy += w * ev.y;
  }
  sm.at.ctxs[sh * 256 + u2 * 2] = cx;
  sm.at.ctxs[sh * 256 + u2 * 2 + 1] = cy;
  __syncthreads();
  st1(ctxb + (ull)row * 288 + tid, sm.at.ctxs[tid] + sm.at.ctxs[256 + tid]);
}

// ---- enc_proj 64x64 gemm tile: P16 = E16 @ We^T ----
__device__ void proj_tile(const __half* E16, const float* attn_w, __half* P16,
                          int m0, int n0, SMT& sm)
{
  const int tid = threadIdx.x;
  const int mq = tid & 15, nq = tid >> 4;
  const int li = tid & 63, kq = tid >> 6;
  float acc[4][4] = {{0.f}};
  for (int k0 = 0; k0 < 256; k0 += 32) {
    float4 raw = *(const float4*)(E16 + (ull)(m0 + li) * 256 + k0 + kq * 8);
    const __half* hp = (const __half*)&raw;
#pragma unroll
    for (int i = 0; i < 8; i++) sm.g.As[kq * 8 + i][li] = __half2float(hp[i]);
    const float* gb = attn_w + (ull)(n0 + li) * 512 + k0 + kq * 8;
    const float4 v0 = *(const float4*)gb, v1 = *(const float4*)(gb + 4);
    sm.g.Bs[kq * 8 + 0][li] = v0.x; sm.g.Bs[kq * 8 + 1][li] = v0.y;
    sm.g.Bs[kq * 8 + 2][li] = v0.z; sm.g.Bs[kq * 8 + 3][li] = v0.w;
    sm.g.Bs[kq * 8 + 4][li] = v1.x; sm.g.Bs[kq * 8 + 5][li] = v1.y;
    sm.g.Bs[kq * 8 + 6][li] = v1.z; sm.g.Bs[kq * 8 + 7][li] = v1.w;
    __syncthreads();
#pragma unroll 8
    for (int kk = 0; kk < 32; kk++) {
      const float4 a4 = *(const float4*)&sm.g.As[kk][mq * 4];
      const float4 b4 = *(const float4*)&sm.g.Bs[kk][nq * 4];
      acc[0][0] += a4.x * b4.x; acc[0][1] += a4.x * b4.y; acc[0][2] += a4.x * b4.z; acc[0][3] += a4.x * b4.w;
      acc[1][0] += a4.y * b4.x; acc[1][1] += a4.y * b4.y; acc[1][2] += a4.y * b4.z; acc[1][3] += a4.y * b4.w;
      acc[2][0] += a4.z * b4.x; acc[2][1] += a4.z * b4.y; acc[2][2] += a4.z * b4.z; acc[2][3] += a4.z * b4.w;
      acc[3][0] += a4.w * b4.x; acc[3][1] += a4.w * b4.y; acc[3][2] += a4.w * b4.z; acc[3][3] += a4.w * b4.w;
    }
    __syncthreads();
  }
#pragma unroll
  for (int i = 0; i < 4; i++) {
    const int m = m0 + mq * 4 + i;
#pragma unroll
    for (int j = 0; j < 2; j++) {
      __half2 h2; h2.x = __float2half(acc[i][j * 2]); h2.y = __float2half(acc[i][j * 2 + 1]);
      stu((unsigned*)(P16 + (ull)m * 256 + n0 + nq * 4) + j, *(unsigned*)&h2);
    }
  }
}

// ---------------------------------------------------------------------------
__global__ __launch_bounds__(256, 1) void seq2seq_pipe(
    const float* __restrict__ src,
    const float* __restrict__ attn_w, const float* __restrict__ attn_b,
    const float* __restrict__ attn_v,
    const float* __restrict__ fc_w, const float* __restrict__ fc_b,
    float* __restrict__ out, int* __restrict__ ib)
{
  __shared__ SMT sm;
  const int blk = blockIdx.x;
  const int tid = threadIdx.x;
  float* fb = (float*)ib + 65536;
  float* y0r  = fb + O_Y0;
  float* h1r  = fb + O_H1;
  float* h0r  = fb + O_H0;
  float* ctxb = fb + O_CTX;
  const float* wT0 = fb + O_WT0;
  const float* wT1 = fb + O_WT1;
  const float* wD0 = fb + O_WD0;
  const float* wD1 = fb + O_WD1;
  const float* wdT = fb + O_WDT;
  const float* bp  = fb + O_BP;
  __half* E16 = (__half*)(fb + O_E16);
  __half* P16 = (__half*)(fb + O_P16);
  int* if0 = ib + IF0; int* if1 = ib + IF1; int* ifa = ib + IFA;
  int* ifh0 = ib + IFH0; int* ifh1 = ib + IFH1; int* ifp = ib + IFP;

  float cReg[4] = {0.f, 0.f, 0.f, 0.f};

  if (blk < 128) {
    // ======== encoder layer 0: 8 u-slices x 16 batch-groups (32 rows) ========
    const int ut0 = blk >> 4, bt0 = blk & 15;
    const int row0 = bt0 * 32, gc0 = ut0 * 128;
    const int bq = tid & 7, ul = tid >> 3;
    const int u = ut0 * 32 + ul;
    const float4 bv = *(const float4*)(bp + gc0 + ul * 4);
    for (int t = 0; t < SS; t++) {
      flag_wait3(t ? if0 + (t - 1) * 16 + bt0 : nullptr, 8,
                 t >= 4 ? if1 + (t - 4) * 8 + (bt0 >> 1) : nullptr, 16, nullptr, 0);
      float acc[4][4];
#pragma unroll
      for (int bd = 0; bd < 4; bd++) { acc[bd][0] = bv.x; acc[bd][1] = bv.y; acc[bd][2] = bv.z; acc[bd][3] = bv.w; }
      // x segment (16 k): src cached loads
      {
        const int r = tid & 31, f = tid >> 5;
        sm.a.Hs[f][r]     = src[((ull)(row0 + r) * SS + t) * 16 + f];
        sm.a.Hs[f + 8][r] = src[((ull)(row0 + r) * SS + t) * 16 + f + 8];
      }
      stage_W128h(wT0, gc0, sm.a.Ws);
      __syncthreads();
      comp128(sm.a.Ws, sm.a.Hs, bq, ul, acc, 16);
      __syncthreads();
      // h segment (256 k) from y0 ring slot (t-1)&3
      const float* hsrc = y0r + (ull)((t + 3) & 3) * BH;
      for (int c8 = 0; c8 < 8; c8++) {
        stage_W128(wT0 + (ull)(16 + c8 * 32) * 1024, gc0, sm.a.Ws);
        stage_H32(hsrc, 256, row0, c8 * 32, t == 0, sm.a.Hs);
        __syncthreads();
        comp128(sm.a.Ws, sm.a.Hs, bq, ul, acc, 32);
        __syncthreads();
      }
      float* yo = y0r + (ull)(t & 3) * BH;
#pragma unroll
      for (int bd = 0; bd < 4; bd++) {
        const int row = row0 + bq * 4 + bd;
        const float iv = sigf(acc[bd][0]), fv = sigf(acc[bd][1]);
        const float gv = tanhf(acc[bd][2]), ov = sigf(acc[bd][3]);
        const float cn = fv * cReg[bd] + iv * gv;
        cReg[bd] = cn;
        st1(yo + (ull)row * 256 + u, ov * tanhf(cn));
      }
      flag_arrive(if0 + t * 16 + bt0);
    }
  } else {
    // ======== encoder layer 1: 16 u-slices x 8 batch-groups (64 rows) ========
    const int b2 = blk - 128;
    const int ut1 = b2 >> 3, bt1 = b2 & 7;
    const int row0 = bt1 * 64, gc0 = ut1 * 64;
    const int rq = tid & 15, ul = tid >> 4;
    const int u = ut1 * 16 + ul;
    const float4 bv = *(const float4*)(bp + 1024 + gc0 + ul * 4);
    for (int s = 0; s < SS; s++) {
      flag_wait3(if0 + s * 16 + bt1 * 2, 8, if0 + s * 16 + bt1 * 2 + 1, 8,
                 s ? if1 + (s - 1) * 8 + bt1 : nullptr, 16);
      float acc[4][4];
#pragma unroll
      for (int bd = 0; bd < 4; bd++) { acc[bd][0] = bv.x; acc[bd][1] = bv.y; acc[bd][2] = bv.z; acc[bd][3] = bv.w; }
      const float* ysrc = y0r + (ull)(s & 3) * BH;
      const float* hsrc = h1r + (ull)((s + 1) & 1) * BH;
      for (int c8 = 0; c8 < 16; c8++) {
        stage_W64(wT1 + (ull)(c8 * 32) * 1024, gc0, sm.b.Ws);
        if (c8 < 8) stage_H64(ysrc, row0, c8 * 32, 0, sm.b.Hs);
        else        stage_H64(hsrc, row0, (c8 - 8) * 32, s == 0, sm.b.Hs);
        __syncthreads();
        comp64(sm.b.Ws, sm.b.Hs, rq, ul, acc);
        __syncthreads();
      }
      float* ho = h1r + (ull)(s & 1) * BH;
#pragma unroll
      for (int bd = 0; bd < 4; bd++) {
        const int row = row0 + rq * 4 + bd;
        const float iv = sigf(acc[bd][0]), fv = sigf(acc[bd][1]);
        const float gv = tanhf(acc[bd][2]), ov = sigf(acc[bd][3]);
        const float cn = fv * cReg[bd] + iv * gv;
        cReg[bd] = cn;
        const float hn = ov * tanhf(cn);
        st1(ho + (ull)row * 256 + u, hn);
        sth(E16 + ((ull)row * SS + s) * 256 + u, __float2half(hn));
      }
      flag_arrive(if1 + s * 8 + bt1);
    }
  }

  // ======== enc_proj: all 256 blocks, 21 tiles each ========
  if (tid < 8) poll(if1 + 167 * 8 + tid, 16);
  __syncthreads();
  for (int tile = blk; tile < (BB * SS / 64) * 4; tile += NBLK)
    proj_tile(E16, attn_w, P16, (tile >> 2) * 64, (tile & 3) * 64, sm);
  flag_arrive(ifp);

  // ======== decoder ========
  // NOTE: cReg is NOT reset here. Reference decoder carries start from the
  // encoder finals: cell0 from (h0e, c0e) = enc layer0 final (h,c); cell1
  // from (h1e, c1e) = enc layer1 final. Both live in cReg with the exact
  // same (row,u) partition as the decoder cells use. (R4 zeroed cell0's
  // cReg -> absmax 7.2e-3; this is the fix.)
  for (int t = 0; t <= TT; t++) {
    if (t == 0) flag_wait3(ifp, NBLK, nullptr, 0, nullptr, 0);
    else flag_wait3(ifh1 + (t - 1) * 8 + (blk >> 5), 16, nullptr, 0, nullptr, 0);
    const int slot = (t + 1) & 1;
    attn_fc(2 * blk,     t, slot, h1r, wdT, attn_b, attn_v, P16, E16, fc_w, fc_b, ctxb, out, sm);
    attn_fc(2 * blk + 1, t, slot, h1r, wdT, attn_b, attn_v, P16, E16, fc_w, fc_b, ctxb, out, sm);
    if (t == TT) break;
    flag_arrive(ifa + t * 16 + (blk >> 4));
    if (blk < 128) {
      // ---- dec cell0: x = [ctx(256) | h0prev(256) | pred(1)] ----
      const int ut0 = blk >> 4, bt0 = blk & 15;
      const int row0 = bt0 * 32, gc0 = ut0 * 128;
      const int bq = tid & 7, ul = tid >> 3;
      const int u = ut0 * 32 + ul;
      flag_wait3(ifa + t * 16 + bt0, 16, t ? ifh0 + (t - 1) * 16 + bt0 : nullptr, 8, nullptr, 0);
      const float4 bv = *(const float4*)(bp + 2048 + gc0 + ul * 4);
      float acc[4][4];
#pragma unroll
      for (int bd = 0; bd < 4; bd++) { acc[bd][0] = bv.x; acc[bd][1] = bv.y; acc[bd][2] = bv.z; acc[bd][3] = bv.w; }
      const float* h0src = (t == 0) ? y0r + 3 * BH : h0r + (ull)((t + 1) & 1) * BH;
      for (int c8 = 0; c8 < 16; c8++) {
        stage_W128(wD0 + (ull)(c8 * 32) * 1024, gc0, sm.a.Ws);
        if (c8 < 8) stage_H32(ctxb, 288, row0, c8 * 32, 0, sm.a.Hs);
        else        stage_H32(h0src, 256, row0, (c8 - 8) * 32, 0, sm.a.Hs);
        __syncthreads();
        comp128(sm.a.Ws, sm.a.Hs, bq, ul, acc, 32);
        __syncthreads();
      }
      const float4 wp = *(const float4*)(wD0 + 512ull * 1024 + gc0 + ul * 4);
      float* ho = h0r + (ull)(t & 1) * BH;
#pragma unroll
      for (int bd = 0; bd < 4; bd++) {
        const int row = row0 + bq * 4 + bd;
        const float p = ld1(ctxb + (ull)row * 288 + 256);
        acc[bd][0] += p * wp.x; acc[bd][1] += p * wp.y; acc[bd][2] += p * wp.z; acc[bd][3] += p * wp.w;
        const float iv = sigf(acc[bd][0]), fv = sigf(acc[bd][1]);
        const float gv = tanhf(acc[bd][2]), ov = sigf(acc[bd][3]);
        const float cn = fv * cReg[bd] + iv * gv;
        cReg[bd] = cn;
        st1(ho + (ull)row * 256 + u, ov * tanhf(cn));
      }
      flag_arrive(ifh0 + t * 16 + bt0);
    } else {
      // ---- dec cell1: x = [h0new(256) | h1prev(256)] ----
      const int b2 = blk - 128;
      const int ut1 = b2 >> 3, bt1 = b2 & 7;
      const int row0 = bt1 * 64, gc0 = ut1 * 64;
      const int rq = tid & 15, ul = tid >> 4;
      const int u = ut1 * 16 + ul;
      flag_wait3(ifh0 + t * 16 + bt1 * 2, 8, ifh0 + t * 16 + bt1 * 2 + 1, 8,
                 t ? ifh1 + (t - 1) * 8 + bt1 : nullptr, 16);
      const float4 bv = *(const float4*)(bp + 3072 + gc0 + ul * 4);
      float acc[4][4];
#pragma unroll
      for (int bd = 0; bd < 4; bd++) { acc[bd][0] = bv.x; acc[bd][1] = bv.y; acc[bd][2] = bv.z; acc[bd][3] = bv.w; }
      const float* h0src = h0r + (ull)(t & 1) * BH;
      const float* h1src = h1r + (ull)((t + 1) & 1) * BH;
      for (int c8 = 0; c8 < 16; c8++) {
        stage_W64(wD1 + (ull)(c8 * 32) * 1024, gc0, sm.b.Ws);
        if (c8 < 8) stage_H64(h0src, row0, c8 * 32, 0, sm.b.Hs);
        else        stage_H64(h1src, row0, (c8 - 8) * 32, 0, sm.b.Hs);
        __syncthreads();
        comp64(sm.b.Ws, sm.b.Hs, rq, ul, acc);
        __syncthreads();
      }
      float* ho = h1r + (ull)(t & 1) * BH;
#pragma unroll
      for (int bd = 0; bd < 4; bd++) {
        const int row = row0 + rq * 4 + bd;
        const float iv = sigf(acc[bd][0]), fv = sigf(acc[bd][1]);
        const float gv = tanhf(acc[bd][2]), ov = sigf(acc[bd][3]);
        const float cn = fv * cReg[bd] + iv * gv;
        cReg[bd] = cn;
        st1(ho + (ull)row * 256 + u, ov * tanhf(cn));
      }
      flag_arrive(ifh1 + t * 8 + bt1);
    }
  }
}

// ---------------------------------------------------------------------------
// Init kernel: zero flags, pre-transpose weights (col = u*4+gate), pack
// biases, seed ctx pred col with dec_in0.
// ---------------------------------------------------------------------------
__global__ void init_all(
    const float* __restrict__ src,
    const float* __restrict__ ewih0, const float* __restrict__ ewhh0, const float* __restrict__ eb0,
    const float* __restrict__ ewih1, const float* __restrict__ ewhh1, const float* __restrict__ eb1,
    const float* __restrict__ dwih0, const float* __restrict__ dwhh0, const float* __restrict__ db0,
    const float* __restrict__ dwih1, const float* __restrict__ dwhh1, const float* __restrict__ db1,
    const float* __restrict__ attn_w, int* __restrict__ ib)
{
  const int gid = blockIdx.x * 256 + threadIdx.x;
  const int NG = 1024 * 256;
  float* fb = (float*)ib + 65536;
  for (int i = gid; i < 8192; i += NG) ib[i] = 0;
  for (int i = gid; i < 272 * 1024; i += NG) {
    const int k = i >> 10, cg = i & 1023, j = (cg & 3) * 256 + (cg >> 2);
    fb[O_WT0 + i] = (k < 16) ? ewih0[(ull)j * 16 + k] : ewhh0[(ull)j * 256 + k - 16];
  }
  for (int i = gid; i < 512 * 1024; i += NG) {
    const int k = i >> 10, cg = i & 1023, j = (cg & 3) * 256 + (cg >> 2);
    fb[O_WT1 + i] = (k < 256) ? ewih1[(ull)j * 256 + k] : ewhh1[(ull)j * 256 + k - 256];
  }
  for (int i = gid; i < 513 * 1024; i += NG) {
    const int k = i >> 10, cg = i & 1023, j = (cg & 3) * 256 + (cg >> 2);
    float v;
    if (k < 256) v = dwih0[(ull)j * 257 + 1 + k];
    else if (k < 512) v = dwhh0[(ull)j * 256 + k - 256];
    else v = dwih0[(ull)j * 257];
    fb[O_WD0 + i] = v;
  }
  for (int i = gid; i < 512 * 1024; i += NG) {
    const int k = i >> 10, cg = i & 1023, j = (cg & 3) * 256 + (cg >> 2);
    fb[O_WD1 + i] = (k < 256) ? dwih1[(ull)j * 256 + k] : dwhh1[(ull)j * 256 + k - 256];
  }
  for (int i = gid; i < 256 * 256; i += NG) {
    const int k = i >> 8, g = i & 255;
    fb[O_WDT + i] = attn_w[(ull)g * 512 + 256 + k];
  }
  for (int i = gid; i < 4096; i += NG) {
    const int set = i >> 10, cg = i & 1023, j = (cg & 3) * 256 + (cg >> 2);
    const float* bsrc = (set == 0) ? eb0 : (set == 1) ? eb1 : (set == 2) ? db0 : db1;
    fb[O_BP + i] = bsrc[j];
  }
  for (int i = gid; i < 512; i += NG)
    fb[O_CTX + (ull)i * 288 + 256] = src[((ull)i * SS + 167) * 16 + 15];
}

extern "C" void kernel_launch(void* const* d_in, const int* in_sizes, int n_in,
                              void* d_out, int out_size, void* d_ws, size_t ws_size,
                              hipStream_t stream)
{
  const float* src    = (const float*)d_in[0];
  const float* ewih0  = (const float*)d_in[1];
  const float* ewhh0  = (const float*)d_in[2];
  const float* eb0    = (const float*)d_in[3];
  const float* ewih1  = (const float*)d_in[4];
  const float* ewhh1  = (const float*)d_in[5];
  const float* eb1    = (const float*)d_in[6];
  const float* dwih0  = (const float*)d_in[7];
  const float* dwhh0  = (const float*)d_in[8];
  const float* db0    = (const float*)d_in[9];
  const float* dwih1  = (const float*)d_in[10];
  const float* dwhh1  = (const float*)d_in[11];
  const float* db1    = (const float*)d_in[12];
  const float* attn_w = (const float*)d_in[13];
  const float* attn_b = (const float*)d_in[14];
  const float* attn_v = (const float*)d_in[15];
  // d_in[16] pos_bias: post-tanh, uniform over s -> softmax-invariant, unused.
  const float* fc_w   = (const float*)d_in[17];
  const float* fc_b   = (const float*)d_in[18];
  float* out = (float*)d_out;
  int* ib    = (int*)d_ws;

  init_all<<<1024, 256, 0, stream>>>(src, ewih0, ewhh0, eb0, ewih1, ewhh1, eb1,
                                     dwih0, dwhh0, db0, dwih1, dwhh1, db1, attn_w, ib);

  void* args[] = {
    (void*)&src, (void*)&attn_w, (void*)&attn_b, (void*)&attn_v,
    (void*)&fc_w, (void*)&fc_b, (void*)&out, (void*)&ib,
  };
  hipLaunchCooperativeKernel((const void*)seq2seq_pipe, dim3(NBLK), dim3(NTHR),
                             args, 0, stream);
}